// Round 6
// baseline (1365.487 us; speedup 1.0000x reference)
//
#include <hip/hip_runtime.h>

#define L2E 1.44269504088896340736f

// ---- workspace layout (bytes) ----
// [0,262144)          ull  slotS64[2][8][16][128]  (score partials, self-tagged, ring-2)
// [262144,264192)     float gEmbWo[512]
// [264192,1312768)    uint gICoB[8][128][256]      (X@Co as packed bf16 pairs)
// [1313792,5508096)   float gXW[1024][1024]        (X@[Ua|Uo], row stride 1024)
// No init needed: 0xAA poison never matches tags 1..128.

typedef unsigned long long ull;

__device__ __forceinline__ void st_pack(ull* p, float v, int tag) {
  ull u = (((ull)(unsigned)tag) << 32) | (ull)__float_as_uint(v);
  __hip_atomic_store(p, u, __ATOMIC_RELAXED, __HIP_MEMORY_SCOPE_AGENT);
}
__device__ __forceinline__ ull ld_pack(const ull* p) {
  return __hip_atomic_load(p, __ATOMIC_RELAXED, __HIP_MEMORY_SCOPE_AGENT);
}
__device__ __forceinline__ unsigned bf16rne(float x) {
  unsigned u = __float_as_uint(x);
  return (u + 0x7FFFu + ((u >> 16) & 1u)) >> 16;
}

// ---- precompute GEMM: cols 0..1023 -> f32 gXW (Ua|Uo); cols 1024.. -> bf16 gICoB ----
__global__ __launch_bounds__(256) void gemm_pre(
    const float* __restrict__ A, const float* __restrict__ Ua,
    const float* __restrict__ Uo, const float* __restrict__ Co,
    float* __restrict__ XW, unsigned* __restrict__ ICoB)
{
  __shared__ float sA[64][33];
  __shared__ float sB[32][68];
  const int r0 = blockIdx.x * 64;
  const int c0 = blockIdx.y * 64;
  const float* Wm; int cc0;
  if (c0 < 512)       { Wm = Ua; cc0 = c0; }
  else if (c0 < 1024) { Wm = Uo; cc0 = c0 - 512; }
  else                { Wm = Co; cc0 = c0 - 1024; }
  const int tid = threadIdx.x;
  const int ty4 = (tid >> 4) * 4;
  const int tx4 = (tid & 15) * 4;
  float acc[4][4] = {};
  for (int k0 = 0; k0 < 512; k0 += 32) {
    for (int t4 = tid; t4 < 512; t4 += 256) {
      int row = t4 >> 3, kq = (t4 & 7) << 2;
      float4 v = *reinterpret_cast<const float4*>(&A[(size_t)(r0 + row) * 512 + k0 + kq]);
      sA[row][kq] = v.x; sA[row][kq + 1] = v.y; sA[row][kq + 2] = v.z; sA[row][kq + 3] = v.w;
    }
    for (int t4 = tid; t4 < 512; t4 += 256) {
      int kk = t4 >> 4, cq = (t4 & 15) << 2;
      float4 v = *reinterpret_cast<const float4*>(&Wm[(size_t)(k0 + kk) * 512 + cc0 + cq]);
      sB[kk][cq] = v.x; sB[kk][cq + 1] = v.y; sB[kk][cq + 2] = v.z; sB[kk][cq + 3] = v.w;
    }
    __syncthreads();
    #pragma unroll 8
    for (int kk = 0; kk < 32; ++kk) {
      float a0 = sA[ty4 + 0][kk], a1 = sA[ty4 + 1][kk];
      float a2 = sA[ty4 + 2][kk], a3 = sA[ty4 + 3][kk];
      float4 bv = *reinterpret_cast<const float4*>(&sB[kk][tx4]);
      acc[0][0] += a0 * bv.x; acc[0][1] += a0 * bv.y; acc[0][2] += a0 * bv.z; acc[0][3] += a0 * bv.w;
      acc[1][0] += a1 * bv.x; acc[1][1] += a1 * bv.y; acc[1][2] += a1 * bv.z; acc[1][3] += a1 * bv.w;
      acc[2][0] += a2 * bv.x; acc[2][1] += a2 * bv.y; acc[2][2] += a2 * bv.z; acc[2][3] += a2 * bv.w;
      acc[3][0] += a3 * bv.x; acc[3][1] += a3 * bv.y; acc[3][2] += a3 * bv.z; acc[3][3] += a3 * bv.w;
    }
    __syncthreads();
  }
  if (c0 < 1024) {
    for (int i = 0; i < 4; ++i) {
      float4 v = make_float4(acc[i][0], acc[i][1], acc[i][2], acc[i][3]);
      *reinterpret_cast<float4*>(&XW[(size_t)(r0 + ty4 + i) * 1024 + c0 + tx4]) = v;
    }
  } else {
    const int ob = c0 - 1024 + tx4;   // multiple of 4
    for (int i = 0; i < 4; ++i) {
      int row = r0 + ty4 + i;         // row = b*128 + t
      unsigned w0 = bf16rne(acc[i][0]) | (bf16rne(acc[i][1]) << 16);
      unsigned w1 = bf16rne(acc[i][2]) | (bf16rne(acc[i][3]) << 16);
      uint2 w = make_uint2(w0, w1);
      *reinterpret_cast<uint2*>(&ICoB[(size_t)row * 256 + (ob >> 1)]) = w;
    }
  }
}

// ---------------- embWo[k] = sum_o emb[k][o] * Wo[o] ----------------
__global__ __launch_bounds__(512) void embwo_kernel(
    const float* __restrict__ emb, const float* __restrict__ Wo,
    float* __restrict__ gEmbWo)
{
  const int lane = threadIdx.x & 63;
  const int wv = threadIdx.x >> 6;
  const int kbase = blockIdx.x * 64 + wv * 8;
  for (int i = 0; i < 8; ++i) {
    const int k = kbase + i;
    float acc = 0.f;
    #pragma unroll
    for (int c = 0; c < 8; ++c) {
      int o = lane + 64 * c;
      acc += emb[(size_t)k * 512 + o] * Wo[o];
    }
    #pragma unroll
    for (int d = 1; d < 64; d <<= 1) acc += __shfl_xor(acc, d);
    if (lane == 0) gEmbWo[k] = acc;
  }
}

// ------- scan: 8 batches x 16 blocks, 256 thr; ONE exchange/step (scores) -------
__global__ __launch_bounds__(256) void coop_scan(
    const float* __restrict__ Wa, const float* __restrict__ Va,
    const float* __restrict__ Ba, const float* __restrict__ Bo,
    const float* __restrict__ gXW, const unsigned* __restrict__ gICoB,
    const float* __restrict__ gEmbWo, ull* slotS64, float* __restrict__ out)
{
  extern __shared__ float smem[];
  float* sWa    = smem;             // [512][32]  Wa[:, oslice]
  float* sUaHT  = smem + 16384;     // [32][129]  UaH^T (+Ba)
  float* sPred  = smem + 20512;     // [512]
  float* sS     = smem + 21024;     // [512]
  float* sEmb   = smem + 21536;     // [512]
  float* sBo    = smem + 22048;     // [512]
  float* sP1row = smem + 22560;     // [512]
  float* sSm    = smem + 23072;     // [128]
  float* sRedB  = smem + 23200;     // [8][32]
  float* sRed   = smem + 23456;     // [16]
  float* sVa    = smem + 23472;     // [32]
  float* sWaS   = smem + 23504;     // [32]

  const int tid = threadIdx.x;
  const int lane = tid & 63;
  const int wv = tid >> 6;        // 0..3
  const int b = blockIdx.x & 7;   // batch (XCD-local heuristic only)
  const int j = blockIdx.x >> 3;  // o-slice 0..15
  const int obase = j * 32;
  const int u = tid;              // owns pred elements 2u, 2u+1

  // ---- prologue ----
  for (int idx = tid; idx < 512 * 32; idx += 256) {
    int k = idx >> 5, oo = idx & 31;
    sWa[idx] = Wa[(size_t)k * 512 + obase + oo];
  }
  for (int idx = tid; idx < 128 * 32; idx += 256) {
    int tt = idx >> 5, oo = idx & 31;
    int col = obase + oo;
    sUaHT[oo * 129 + tt] = gXW[(size_t)(b * 128 + tt) * 1024 + col] + Ba[col];
  }
  if (tid < 32) sVa[tid] = Va[obase + tid];
  sEmb[tid] = gEmbWo[tid];       sEmb[tid + 256] = gEmbWo[tid + 256];
  sBo[tid]  = Bo[tid];           sBo[tid + 256]  = Bo[tid + 256];
  sPred[tid] = 0.f;              sPred[tid + 256] = 0.f;

  const unsigned* myICo = gICoB + (size_t)b * 32768;   // [128][256] packed pairs

  for (int t = 0; t < 128; ++t) {
    __syncthreads();  // (A) sPred ready

    // ---- phase 1: sigmoid + softmax-O stats + P1-row prefetch ----
    float p1 = sPred[tid], p2 = sPred[tid + 256];
    sS[tid]       = 1.f / (1.f + exp2f(-p1 * L2E));
    sS[tid + 256] = 1.f / (1.f + exp2f(-p2 * L2E));
    {
      const int tprev = (t + 127) & 127;
      const float* uorow = gXW + (size_t)(b * 128 + tprev) * 1024 + 512;
      sP1row[tid]       = uorow[tid] + sBo[tid];
      sP1row[tid + 256] = uorow[tid + 256] + sBo[tid + 256];
    }
    float e1 = exp2f(p1 * L2E), e2 = exp2f(p2 * L2E);
    float Ep = e1 + e2;
    float Dp = e1 * sEmb[tid] + e2 * sEmb[tid + 256];
    #pragma unroll
    for (int d = 1; d < 64; d <<= 1) { Ep += __shfl_xor(Ep, d); Dp += __shfl_xor(Dp, d); }
    if (lane == 0) { sRed[wv] = Ep; sRed[4 + wv] = Dp; }
    __syncthreads();  // (B)
    const float WoY = (sRed[4] + sRed[5] + sRed[6] + sRed[7])
                    / (sRed[0] + sRed[1] + sRed[2] + sRed[3]);

    // ---- phase 2: WaS[oslice] = sum_k s[k]*Wa[k,oslice] ----
    {
      const int o = tid & 31, kg = tid >> 5, kb = kg * 64;
      float acc = 0.f;
      #pragma unroll 16
      for (int i = 0; i < 64; ++i) acc += sS[kb + i] * sWa[(kb + i) * 32 + o];
      sRedB[kg * 32 + o] = acc;
    }
    __syncthreads();  // (C)
    if (tid < 32) {
      float w = 0.f;
      #pragma unroll
      for (int g = 0; g < 8; ++g) w += sRedB[g * 32 + tid];
      sWaS[tid] = w;
    }
    __syncthreads();  // (D)

    // ---- phase 3: partial scores over own o-slice; self-tagged publish ----
    {
      const int h = tid & 1, tp = tid >> 1;
      float acc = 0.f;
      #pragma unroll
      for (int i = 0; i < 16; ++i) {
        const int oo = h * 16 + i;
        float uu = sUaHT[oo * 129 + tp] + sWaS[oo];
        float ex = exp2f(uu * (2.f * L2E));
        acc += (1.f - 2.f / (1.f + ex)) * sVa[oo];   // tanh(u)*Va
      }
      acc += __shfl_xor(acc, 1);
      if (h == 0)
        st_pack(slotS64 + (((t & 1) * 8 + b) * 16 + j) * 128 + tp, acc, t + 1);
    }

    // ---- phase 4: poll-gather tagged partials; softmax over T ----
    if (tid < 128) {
      const ull* basep = slotS64 + ((t & 1) * 8 + b) * 2048 + tid;
      const unsigned want = (unsigned)(t + 1);
      float sc = 0.f;
      unsigned mask = 0xFFFFu;
      while (mask) {
        #pragma unroll
        for (int jj = 0; jj < 16; ++jj) {
          if (mask & (1u << jj)) {
            ull v = ld_pack(basep + jj * 128);
            if ((unsigned)(v >> 32) == want) {
              sc += __uint_as_float((unsigned)v);
              mask &= ~(1u << jj);
            }
          }
        }
      }
      float ev = exp2f(sc * L2E);
      sSm[tid] = ev;
      float sv = ev;
      #pragma unroll
      for (int d = 1; d < 64; d <<= 1) sv += __shfl_xor(sv, d);
      if (lane == 0) sRed[8 + wv] = sv;   // wv in {0,1}
    }
    __syncthreads();  // (G)
    const float rden = 1.f / (sRed[8] + sRed[9]);

    // ---- phase 5: FULL pred redundantly: WoY + P1row + (sm@ICo)/den ----
    {
      float a0 = 0.f, a1 = 0.f;
      const unsigned* col = myICo + u;
      #pragma unroll 8
      for (int tt = 0; tt < 128; ++tt) {
        float s = sSm[tt];
        unsigned w = col[(size_t)tt * 256];
        a0 = fmaf(s, __uint_as_float(w << 16), a0);
        a1 = fmaf(s, __uint_as_float(w & 0xFFFF0000u), a1);
      }
      float pred0 = WoY + sP1row[2 * u]     + a0 * rden;
      float pred1 = WoY + sP1row[2 * u + 1] + a1 * rden;
      sPred[2 * u]     = pred0;
      sPred[2 * u + 1] = pred1;
      if (u >= (obase >> 1) && u < (obase >> 1) + 16) {
        *reinterpret_cast<float2*>(&out[((size_t)(b * 128 + t)) * 512 + 2 * u]) =
            make_float2(pred0, pred1);
      }
    }
  }
}

extern "C" void kernel_launch(void* const* d_in, const int* in_sizes, int n_in,
                              void* d_out, int out_size, void* d_ws, size_t ws_size,
                              hipStream_t stream)
{
  const float* inputs = (const float*)d_in[0];
  const float* Wa  = (const float*)d_in[1];
  const float* Ua  = (const float*)d_in[2];
  const float* Va  = (const float*)d_in[3];
  const float* Ba  = (const float*)d_in[4];
  const float* Wo  = (const float*)d_in[5];
  const float* Uo  = (const float*)d_in[6];
  const float* Co  = (const float*)d_in[7];
  const float* Bo  = (const float*)d_in[8];
  const float* emb = (const float*)d_in[9];
  float* out = (float*)d_out;

  char* ws = (char*)d_ws;
  ull*      slotS64 = (ull*)(ws + 0);
  float*    gEmbWo  = (float*)(ws + 262144);
  unsigned* gICoB   = (unsigned*)(ws + 264192);
  float*    gXW     = (float*)(ws + 1313792);

  dim3 gg(16, 24);
  gemm_pre<<<gg, 256, 0, stream>>>(inputs, Ua, Uo, Co, gXW, gICoB);
  embwo_kernel<<<8, 512, 0, stream>>>(emb, Wo, gEmbWo);

  const int smem_bytes = 23536 * 4;  // 94144 B dynamic LDS
  hipFuncSetAttribute((const void*)coop_scan,
                      hipFuncAttributeMaxDynamicSharedMemorySize, smem_bytes);
  coop_scan<<<128, 256, smem_bytes, stream>>>(Wa, Va, Ba, Bo, gXW, gICoB,
                                              gEmbWo, slotS64, out);
}

// Round 11
// 1346.944 us; speedup vs baseline: 1.0138x; 1.0138x over previous
//
#include <hip/hip_runtime.h>

#define L2E 1.44269504088896340736f

// ---- workspace layout (bytes) ----
// [0,262144)          ull  slotS64[2][8][16][128]  (score partials, self-tagged, ring-2)
// [262144,264192)     float gEmbWo[512]
// [264192,1312768)    uint gICoB[8][128][256]      (X@Co as packed bf16 pairs)
// [1313792,5508096)   float gXW[1024][1024]        (X@[Ua|Uo], row stride 1024)
// No init needed: 0xAA poison never matches tags 1..128.

typedef unsigned long long ull;

__device__ __forceinline__ void st_pack(ull* p, float v, int tag) {
  ull u = (((ull)(unsigned)tag) << 32) | (ull)__float_as_uint(v);
  __hip_atomic_store(p, u, __ATOMIC_RELAXED, __HIP_MEMORY_SCOPE_AGENT);
}
__device__ __forceinline__ ull ld_pack(const ull* p) {
  return __hip_atomic_load(p, __ATOMIC_RELAXED, __HIP_MEMORY_SCOPE_AGENT);
}
__device__ __forceinline__ unsigned bf16rne(float x) {
  unsigned u = __float_as_uint(x);
  return (u + 0x7FFFu + ((u >> 16) & 1u)) >> 16;
}

// ---- precompute GEMM: cols 0..1023 -> f32 gXW (Ua|Uo); cols 1024.. -> bf16 gICoB ----
__global__ __launch_bounds__(256) void gemm_pre(
    const float* __restrict__ A, const float* __restrict__ Ua,
    const float* __restrict__ Uo, const float* __restrict__ Co,
    float* __restrict__ XW, unsigned* __restrict__ ICoB)
{
  __shared__ float sA[64][33];
  __shared__ float sB[32][68];
  const int r0 = blockIdx.x * 64;
  const int c0 = blockIdx.y * 64;
  const float* Wm; int cc0;
  if (c0 < 512)       { Wm = Ua; cc0 = c0; }
  else if (c0 < 1024) { Wm = Uo; cc0 = c0 - 512; }
  else                { Wm = Co; cc0 = c0 - 1024; }
  const int tid = threadIdx.x;
  const int ty4 = (tid >> 4) * 4;
  const int tx4 = (tid & 15) * 4;
  float acc[4][4] = {};
  for (int k0 = 0; k0 < 512; k0 += 32) {
    for (int t4 = tid; t4 < 512; t4 += 256) {
      int row = t4 >> 3, kq = (t4 & 7) << 2;
      float4 v = *reinterpret_cast<const float4*>(&A[(size_t)(r0 + row) * 512 + k0 + kq]);
      sA[row][kq] = v.x; sA[row][kq + 1] = v.y; sA[row][kq + 2] = v.z; sA[row][kq + 3] = v.w;
    }
    for (int t4 = tid; t4 < 512; t4 += 256) {
      int kk = t4 >> 4, cq = (t4 & 15) << 2;
      float4 v = *reinterpret_cast<const float4*>(&Wm[(size_t)(k0 + kk) * 512 + cc0 + cq]);
      sB[kk][cq] = v.x; sB[kk][cq + 1] = v.y; sB[kk][cq + 2] = v.z; sB[kk][cq + 3] = v.w;
    }
    __syncthreads();
    #pragma unroll 8
    for (int kk = 0; kk < 32; ++kk) {
      float a0 = sA[ty4 + 0][kk], a1 = sA[ty4 + 1][kk];
      float a2 = sA[ty4 + 2][kk], a3 = sA[ty4 + 3][kk];
      float4 bv = *reinterpret_cast<const float4*>(&sB[kk][tx4]);
      acc[0][0] += a0 * bv.x; acc[0][1] += a0 * bv.y; acc[0][2] += a0 * bv.z; acc[0][3] += a0 * bv.w;
      acc[1][0] += a1 * bv.x; acc[1][1] += a1 * bv.y; acc[1][2] += a1 * bv.z; acc[1][3] += a1 * bv.w;
      acc[2][0] += a2 * bv.x; acc[2][1] += a2 * bv.y; acc[2][2] += a2 * bv.z; acc[2][3] += a2 * bv.w;
      acc[3][0] += a3 * bv.x; acc[3][1] += a3 * bv.y; acc[3][2] += a3 * bv.z; acc[3][3] += a3 * bv.w;
    }
    __syncthreads();
  }
  if (c0 < 1024) {
    for (int i = 0; i < 4; ++i) {
      float4 v = make_float4(acc[i][0], acc[i][1], acc[i][2], acc[i][3]);
      *reinterpret_cast<float4*>(&XW[(size_t)(r0 + ty4 + i) * 1024 + c0 + tx4]) = v;
    }
  } else {
    const int ob = c0 - 1024 + tx4;   // multiple of 4
    for (int i = 0; i < 4; ++i) {
      int row = r0 + ty4 + i;         // row = b*128 + t
      unsigned w0 = bf16rne(acc[i][0]) | (bf16rne(acc[i][1]) << 16);
      unsigned w1 = bf16rne(acc[i][2]) | (bf16rne(acc[i][3]) << 16);
      uint2 w = make_uint2(w0, w1);
      *reinterpret_cast<uint2*>(&ICoB[(size_t)row * 256 + (ob >> 1)]) = w;
    }
  }
}

// ---------------- embWo[k] = sum_o emb[k][o] * Wo[o] ----------------
__global__ __launch_bounds__(512) void embwo_kernel(
    const float* __restrict__ emb, const float* __restrict__ Wo,
    float* __restrict__ gEmbWo)
{
  const int lane = threadIdx.x & 63;
  const int wv = threadIdx.x >> 6;
  const int kbase = blockIdx.x * 64 + wv * 8;
  for (int i = 0; i < 8; ++i) {
    const int k = kbase + i;
    float acc = 0.f;
    #pragma unroll
    for (int c = 0; c < 8; ++c) {
      int o = lane + 64 * c;
      acc += emb[(size_t)k * 512 + o] * Wo[o];
    }
    #pragma unroll
    for (int d = 1; d < 64; d <<= 1) acc += __shfl_xor(acc, d);
    if (lane == 0) gEmbWo[k] = acc;
  }
}

// --- scan: 8 batches x 16 blocks, 256 thr; 1 exchange/step; ICo held in VGPRs ---
__global__ __launch_bounds__(256, 1) void coop_scan(
    const float* __restrict__ Wa, const float* __restrict__ Va,
    const float* __restrict__ Ba, const float* __restrict__ Bo,
    const float* __restrict__ gXW, const unsigned* __restrict__ gICoB,
    const float* __restrict__ gEmbWo, ull* slotS64, float* __restrict__ out)
{
  extern __shared__ float smem[];
  float* sWa    = smem;             // [512][32]  Wa[:, oslice]
  float* sUaHT  = smem + 16384;     // [32][129]  UaH^T (+Ba)
  float* sPred  = smem + 20512;     // [512]
  float* sS     = smem + 21024;     // [512]
  float* sEmb   = smem + 21536;     // [512]
  float* sBo    = smem + 22048;     // [512]
  float* sP1row = smem + 22560;     // [512]
  float* sSm    = smem + 23072;     // [128] raw exp(score)
  float* sRedB  = smem + 23200;     // [8][32]
  float* sRed   = smem + 23456;     // [16]
  float* sVa    = smem + 23472;     // [32]
  float* sWaS   = smem + 23504;     // [32]
  float* sPP    = smem + 23536;     // [4][512] per-wave pred partials

  const int tid = threadIdx.x;
  const int lane = tid & 63;
  const int wv = tid >> 6;        // 0..3
  const int b = blockIdx.x & 7;   // batch (XCD-local heuristic only)
  const int j = blockIdx.x >> 3;  // o-slice 0..15
  const int obase = j * 32;

  // ---- prologue ----
  for (int idx = tid; idx < 512 * 32; idx += 256) {
    int k = idx >> 5, oo = idx & 31;
    sWa[idx] = Wa[(size_t)k * 512 + obase + oo];
  }
  for (int idx = tid; idx < 128 * 32; idx += 256) {
    int tt = idx >> 5, oo = idx & 31;
    int col = obase + oo;
    sUaHT[oo * 129 + tt] = gXW[(size_t)(b * 128 + tt) * 1024 + col] + Ba[col];
  }
  if (tid < 32) sVa[tid] = Va[obase + tid];
  sEmb[tid] = gEmbWo[tid];       sEmb[tid + 256] = gEmbWo[tid + 256];
  sBo[tid]  = Bo[tid];           sBo[tid + 256]  = Bo[tid + 256];
  sPred[tid] = 0.f;              sPred[tid + 256] = 0.f;

  // ---- stage ICo in VGPRs, ONCE: wave wv owns rows wv*32..+31, lane owns 8 cols ----
  uint4 rIC[32];
  {
    const unsigned* basep = gICoB + (size_t)b * 32768
                          + (size_t)(wv * 32) * 256 + lane * 4;
    #pragma unroll
    for (int i = 0; i < 32; ++i)
      rIC[i] = *reinterpret_cast<const uint4*>(basep + (size_t)i * 256);
  }

  for (int t = 0; t < 128; ++t) {
    __syncthreads();  // (A) sPred ready

    // ---- phase 1: sigmoid + softmax-O stats + P1-row prefetch ----
    float p1 = sPred[tid], p2 = sPred[tid + 256];
    sS[tid]       = 1.f / (1.f + exp2f(-p1 * L2E));
    sS[tid + 256] = 1.f / (1.f + exp2f(-p2 * L2E));
    {
      const int tprev = (t + 127) & 127;
      const float* uorow = gXW + (size_t)(b * 128 + tprev) * 1024 + 512;
      sP1row[tid]       = uorow[tid] + sBo[tid];
      sP1row[tid + 256] = uorow[tid + 256] + sBo[tid + 256];
    }
    float e1 = exp2f(p1 * L2E), e2 = exp2f(p2 * L2E);
    float Ep = e1 + e2;
    float Dp = e1 * sEmb[tid] + e2 * sEmb[tid + 256];
    #pragma unroll
    for (int d = 1; d < 64; d <<= 1) { Ep += __shfl_xor(Ep, d); Dp += __shfl_xor(Dp, d); }
    if (lane == 0) { sRed[wv] = Ep; sRed[4 + wv] = Dp; }
    __syncthreads();  // (B)
    const float WoY = (sRed[4] + sRed[5] + sRed[6] + sRed[7])
                    / (sRed[0] + sRed[1] + sRed[2] + sRed[3]);

    // ---- phase 2: WaS[oslice] = sum_k s[k]*Wa[k,oslice] ----
    {
      const int o = tid & 31, kg = tid >> 5, kb = kg * 64;
      float acc = 0.f;
      #pragma unroll 16
      for (int i = 0; i < 64; ++i) acc += sS[kb + i] * sWa[(kb + i) * 32 + o];
      sRedB[kg * 32 + o] = acc;
    }
    __syncthreads();  // (C)
    if (tid < 32) {
      float w = 0.f;
      #pragma unroll
      for (int g = 0; g < 8; ++g) w += sRedB[g * 32 + tid];
      sWaS[tid] = w;
    }
    __syncthreads();  // (D)

    // ---- phase 3: partial scores over own o-slice; self-tagged publish ----
    {
      const int h = tid & 1, tp = tid >> 1;
      float acc = 0.f;
      #pragma unroll
      for (int i = 0; i < 16; ++i) {
        const int oo = h * 16 + i;
        float uu = sUaHT[oo * 129 + tp] + sWaS[oo];
        float ex = exp2f(uu * (2.f * L2E));
        acc += (1.f - 2.f / (1.f + ex)) * sVa[oo];   // tanh(u)*Va
      }
      acc += __shfl_xor(acc, 1);
      if (h == 0)
        st_pack(slotS64 + (((t & 1) * 8 + b) * 16 + j) * 128 + tp, acc, t + 1);
    }

    // ---- phase 4: poll-gather tagged partials; softmax over T ----
    if (tid < 128) {
      const ull* basep = slotS64 + ((t & 1) * 8 + b) * 2048 + tid;
      const unsigned want = (unsigned)(t + 1);
      float sc = 0.f;
      unsigned mask = 0xFFFFu;
      while (mask) {
        #pragma unroll
        for (int jj = 0; jj < 16; ++jj) {
          if (mask & (1u << jj)) {
            ull v = ld_pack(basep + jj * 128);
            if ((unsigned)(v >> 32) == want) {
              sc += __uint_as_float((unsigned)v);
              mask &= ~(1u << jj);
            }
          }
        }
      }
      float ev = exp2f(sc * L2E);
      sSm[tid] = ev;
      float sv = ev;
      #pragma unroll
      for (int d = 1; d < 64; d <<= 1) sv += __shfl_xor(sv, d);
      if (lane == 0) sRed[8 + wv] = sv;   // wv in {0,1}
    }
    __syncthreads();  // (G)
    const float rden = 1.f / (sRed[8] + sRed[9]);

    // ---- phase 5: full pred from registers: wave-parallel over rows ----
    {
      float a0 = 0.f, a1 = 0.f, a2 = 0.f, a3 = 0.f;
      float a4 = 0.f, a5 = 0.f, a6 = 0.f, a7 = 0.f;
      const int rbase = wv * 32;
      #pragma unroll
      for (int i = 0; i < 32; ++i) {
        float s = sSm[rbase + i];
        uint4 w = rIC[i];
        a0 = fmaf(s, __uint_as_float(w.x << 16),         a0);
        a1 = fmaf(s, __uint_as_float(w.x & 0xFFFF0000u), a1);
        a2 = fmaf(s, __uint_as_float(w.y << 16),         a2);
        a3 = fmaf(s, __uint_as_float(w.y & 0xFFFF0000u), a3);
        a4 = fmaf(s, __uint_as_float(w.z << 16),         a4);
        a5 = fmaf(s, __uint_as_float(w.z & 0xFFFF0000u), a5);
        a6 = fmaf(s, __uint_as_float(w.w << 16),         a6);
        a7 = fmaf(s, __uint_as_float(w.w & 0xFFFF0000u), a7);
      }
      float* pp = sPP + wv * 512 + lane * 8;
      *reinterpret_cast<float4*>(pp)     = make_float4(a0, a1, a2, a3);
      *reinterpret_cast<float4*>(pp + 4) = make_float4(a4, a5, a6, a7);
    }
    __syncthreads();  // (H)
    {
      float v0 = 0.f, v1 = 0.f;
      #pragma unroll
      for (int w2 = 0; w2 < 4; ++w2) {
        float2 q = *reinterpret_cast<const float2*>(&sPP[w2 * 512 + 2 * tid]);
        v0 += q.x; v1 += q.y;
      }
      float pred0 = WoY + sP1row[2 * tid]     + v0 * rden;
      float pred1 = WoY + sP1row[2 * tid + 1] + v1 * rden;
      sPred[2 * tid]     = pred0;
      sPred[2 * tid + 1] = pred1;
      if (tid >= (obase >> 1) && tid < (obase >> 1) + 16) {
        *reinterpret_cast<float2*>(&out[((size_t)(b * 128 + t)) * 512 + 2 * tid]) =
            make_float2(pred0, pred1);
      }
    }
  }
}

extern "C" void kernel_launch(void* const* d_in, const int* in_sizes, int n_in,
                              void* d_out, int out_size, void* d_ws, size_t ws_size,
                              hipStream_t stream)
{
  const float* inputs = (const float*)d_in[0];
  const float* Wa  = (const float*)d_in[1];
  const float* Ua  = (const float*)d_in[2];
  const float* Va  = (const float*)d_in[3];
  const float* Ba  = (const float*)d_in[4];
  const float* Wo  = (const float*)d_in[5];
  const float* Uo  = (const float*)d_in[6];
  const float* Co  = (const float*)d_in[7];
  const float* Bo  = (const float*)d_in[8];
  const float* emb = (const float*)d_in[9];
  float* out = (float*)d_out;

  char* ws = (char*)d_ws;
  ull*      slotS64 = (ull*)(ws + 0);
  float*    gEmbWo  = (float*)(ws + 262144);
  unsigned* gICoB   = (unsigned*)(ws + 264192);
  float*    gXW     = (float*)(ws + 1313792);

  dim3 gg(16, 24);
  gemm_pre<<<gg, 256, 0, stream>>>(inputs, Ua, Uo, Co, gXW, gICoB);
  embwo_kernel<<<8, 512, 0, stream>>>(emb, Wo, gEmbWo);

  const int smem_bytes = 25584 * 4;  // 102336 B dynamic LDS
  hipFuncSetAttribute((const void*)coop_scan,
                      hipFuncAttributeMaxDynamicSharedMemorySize, smem_bytes);
  coop_scan<<<128, 256, smem_bytes, stream>>>(Wa, Va, Ba, Bo, gXW, gICoB,
                                              gEmbWo, slotS64, out);
}